// Round 8
// baseline (280.920 us; speedup 1.0000x reference)
//
#include <hip/hip_runtime.h>

// Problem constants: B=4, N=4096 -> nPoints=16384
#define KN 32                 // neighbors per point
#define FF 64                 // input feature dim
#define CC 256                // H*D channels (H=16 heads, D=16)
#define KSTRB 264             // K row stride (bf16): K[j][c], 256+8 pad, 528B (16B-aligned)
#define VSTB 36               // Vt row stride (bf16): 32+4 pad, 72B -> 18-dw stride = 2-way free
#define VTOFFB (KN * KSTRB)   // Vt base inside one kv buffer (ushorts) = 8448
#define HALFB (KN * KSTRB + CC * VSTB)  // one kv buffer = 8448 + 9216 = 17664 ushorts
#define NITER 16              // points per block
#define QSTRIDE 264           // ushorts per qAll row; 528B/row -> b128-aligned per (it,h)
#define WSTRIDE 36            // wS stride in floats: 16B-aligned rows for b128 reads

// Faithful-reshape semantics (validated R1/R2):
//   K[b,n,h,k,d] = K_proj[b,n, j=2h+(k>>4), ch=(k&15)*16+d];  V likewise.
//   Q[b,n,h,0,d] = Q_proj[b,n, h*16+d].
// R8: DOUBLE-BUFFERED kvS. Iteration = attention(i) on buf[cur], then
// projection(i+1) into buf[cur^1], then ONE lds_barrier (was two). Removes the
// hard wall between the MFMA phase and the attention phase: waves stagger and
// the projection MFMAs/ds_writes fill attention's LDS-latency shadows.
// acc's live range stays after attention (R2 spill lesson). 81.4KB LDS ->
// exactly 2 blocks/CU. VSTB=36 fixes the R7 Vt 4-way write conflict (now 2-way).

typedef __attribute__((ext_vector_type(8)))  short bf16x8;   // 8 bf16 = 4 VGPRs
typedef __attribute__((ext_vector_type(16))) float f32x16;   // 32x32 MFMA acc
typedef __attribute__((ext_vector_type(4)))  float f32x4;    // 16x16 MFMA acc

__device__ inline unsigned short f2bf(float f) {             // fp32->bf16 RNE (prologue only)
    union { float f; unsigned u; } v; v.f = f;
    unsigned u = v.u + 0x7fffu + ((v.u >> 16) & 1u);
    return (unsigned short)(u >> 16);
}
// HW packed fp32->bf16 RNE: 1 instr per pair.
__device__ inline unsigned cvt_pk_bf16(float a, float b) {
    unsigned r;
    asm("v_cvt_pk_bf16_f32 %0, %1, %2" : "=v"(r) : "v"(a), "v"(b));
    return r;
}
__device__ inline bf16x8 pack8(float4 a, float4 b) {
    union { bf16x8 v; unsigned u[4]; } r;
    r.u[0] = cvt_pk_bf16(a.x, a.y);  r.u[1] = cvt_pk_bf16(a.z, a.w);
    r.u[2] = cvt_pk_bf16(b.x, b.y);  r.u[3] = cvt_pk_bf16(b.z, b.w);
    return r.v;
}
__device__ inline float bflo(unsigned u) { return __uint_as_float(u << 16); }
__device__ inline float bfhi(unsigned u) { return __uint_as_float(u & 0xffff0000u); }

// LDS producer/consumer barrier WITHOUT the __syncthreads vmcnt(0) drain:
// global prefetches (A-row, out-stores) stay in flight across the barrier.
__device__ inline void lds_barrier() {
    asm volatile("s_waitcnt lgkmcnt(0)" ::: "memory");
    __builtin_amdgcn_s_barrier();
}

// Block = 256 threads (4 waves), NITER points per block, 2 blocks/CU (LDS-capped).
__global__ __launch_bounds__(256, 2)
void attn_one(const float* __restrict__ inp,
              const float* __restrict__ query,
              const float* __restrict__ Wq,
              const float* __restrict__ bq,
              const float* __restrict__ Wk,
              const float* __restrict__ bk,
              const float* __restrict__ Wv,
              const float* __restrict__ bv,
              float* __restrict__ out, int nPoints)
{
    __shared__ __align__(16) unsigned short kvS[2 * HALFB];  // 69.0 KB: 2 x (K + Vt)
    __shared__ unsigned short qAllS[NITER * QSTRIDE];        // 8.25 KB: pre-scaled Q, bf16
    __shared__ float wS[16 * WSTRIDE];                       // 2.25 KB: softmax weights

    const int tid  = threadIdx.x;
    const int wave = tid >> 6;
    const int L    = tid & 63;
    const int Lm   = L & 31;       // M/N index inside the 32x32 tile
    const int Lh   = L >> 5;       // k-half selector (32x32x16)
    const int h    = tid >> 4;     // attention head 0..15
    const int d    = tid & 15;     // dim within head
    const int bid  = blockIdx.x;
    const int grid = gridDim.x;

    // ---- stage this block's 16 query rows into kvS scratch (freed later) ----
    float* qIn = (float*)kvS;      // 16 rows x 68 floats (pad 64->68) = 4.3 KB
    {
        const int i  = tid >> 4;           // point slot 0..15
        const int f4 = (tid & 15) * 4;
        const int p  = bid + i * grid;
        if (p < nPoints)
            *(float4*)(qIn + i * 68 + f4) =
                *(const float4*)(query + (size_t)p * FF + f4);
    }

    // ---- prefetch first point's A-row into registers ----
    float4 pf[8];
    {
        const float* arow = inp + (size_t)bid * (KN * FF) + Lm * FF + Lh * 8;
#pragma unroll
        for (int s = 0; s < 4; ++s) {
            pf[2 * s]     = *(const float4*)(arow + s * 16);
            pf[2 * s + 1] = *(const float4*)(arow + s * 16 + 4);
        }
    }

    // ---- Wk/Wv B fragments (validated R2 layout) ----
    // B[k][n]: lane holds k = s*16 + Lh*8 + j, n = chunk*32 + Lm
    bf16x8 Bf[4][4];   // [tile: K0,K1,V0,V1][kstep]
#pragma unroll
    for (int t = 0; t < 4; ++t) {
        const float* W  = (t < 2) ? Wk : Wv;
        const int ch    = (2 * wave + (t & 1)) * 32 + Lm;
#pragma unroll
        for (int s = 0; s < 4; ++s) {
            union { bf16x8 v; unsigned u[4]; } r;
#pragma unroll
            for (int jj = 0; jj < 4; ++jj) {
                const int f = s * 16 + Lh * 8 + 2 * jj;
                r.u[jj] = cvt_pk_bf16(W[(size_t)f * CC + ch], W[(size_t)(f + 1) * CC + ch]);
            }
            Bf[t][s] = r.v;
        }
    }
    // V-tile bias: acc columns share one channel -> scalar per tile
    float biasV[2];
    biasV[0] = bv[(2 * wave + 0) * 32 + Lm];
    biasV[1] = bv[(2 * wave + 1) * 32 + Lm];
    // K-tile bias: swapped-MFMA rows span channels c = chunk*32 + 8g + 4Lh + e
    float4 bkK[2][4];
#pragma unroll
    for (int t = 0; t < 2; ++t)
#pragma unroll
        for (int g = 0; g < 4; ++g)
            bkK[t][g] = *(const float4*)(bk + (2 * wave + t) * 32 + 8 * g + 4 * Lh);

    // ---- Wq B fragments: 4 N-tiles of 16 per wave, K=64 in 2 steps ----
    const int nq = L & 15;
    const int kq = (L >> 4) * 8;
    bf16x8 Bq[4][2];
    float  bqv[4];
#pragma unroll
    for (int tt = 0; tt < 4; ++tt) {
        const int ch = wave * 64 + tt * 16 + nq;
        bqv[tt] = bq[ch];
#pragma unroll
        for (int s = 0; s < 2; ++s) {
            union { bf16x8 v; unsigned u[4]; } r;
#pragma unroll
            for (int jj = 0; jj < 4; ++jj) {
                const int f = s * 32 + kq + 2 * jj;
                r.u[jj] = cvt_pk_bf16(Wq[(size_t)f * CC + ch], Wq[(size_t)(f + 1) * CC + ch]);
            }
            Bq[tt][s] = r.v;
        }
    }

    __syncthreads();   // qIn staged

    // ---- Q-projection MFMA: M=16 points, N=256 channels, K=64 ----
    {
        bf16x8 Aq[2];
        const int im = L & 15;
#pragma unroll
        for (int s = 0; s < 2; ++s) {
            const float* qr = qIn + im * 68 + s * 32 + kq;
            Aq[s] = pack8(*(const float4*)qr, *(const float4*)(qr + 4));
        }
#pragma unroll
        for (int tt = 0; tt < 4; ++tt) {
            f32x4 qa = {bqv[tt], bqv[tt], bqv[tt], bqv[tt]};  // bias via C
#pragma unroll
            for (int s = 0; s < 2; ++s)
                qa = __builtin_amdgcn_mfma_f32_16x16x32_bf16(Aq[s], Bq[tt][s], qa, 0, 0, 0);
            const int ch = wave * 64 + tt * 16 + nq;
#pragma unroll
            for (int r = 0; r < 4; ++r) {
                const int ip = (L >> 4) * 4 + r;    // point slot 0..15
                qAllS[ip * QSTRIDE + ch] = f2bf(qa[r] * 0.25f);
            }
        }
    }
    __syncthreads();   // qAll ready; kvS scratch free

    // ---- projection of one point into kv buffer bp (MFMA + bf16 writeback) ----
    auto project = [&](unsigned short* __restrict__ bp, const bf16x8 (&Af)[4]) {
        // K tiles (0,1): operand-SWAPPED mfma -> D = (X*Wk)^T, col=j, rows=c.
        // V tiles (2,3): normal orientation  -> D = X*Wv,     col=c, rows=j.
        f32x16 acc[4];
#pragma unroll
        for (int t = 0; t < 2; ++t)
#pragma unroll
            for (int g = 0; g < 4; ++g)
#pragma unroll
                for (int e = 0; e < 4; ++e) acc[t][4 * g + e] = bkK[t][g][e];
#pragma unroll
        for (int t = 2; t < 4; ++t)
#pragma unroll
            for (int r = 0; r < 16; ++r) acc[t][r] = biasV[t - 2];

        __builtin_amdgcn_s_setprio(1);
#pragma unroll
        for (int s = 0; s < 4; ++s) {
#pragma unroll
            for (int t = 0; t < 2; ++t)
                acc[t] = __builtin_amdgcn_mfma_f32_32x32x16_bf16(Bf[t][s], Af[s], acc[t], 0, 0, 0);
#pragma unroll
            for (int t = 2; t < 4; ++t)
                acc[t] = __builtin_amdgcn_mfma_f32_32x32x16_bf16(Af[s], Bf[t][s], acc[t], 0, 0, 0);
        }
        __builtin_amdgcn_s_setprio(0);

        // K writeback (bf16): lane = j=Lm; 4x b64 of 4 consecutive channels each
#pragma unroll
        for (int t = 0; t < 2; ++t) {
            unsigned short* kr = bp + Lm * KSTRB + (2 * wave + t) * 32 + 4 * Lh;
#pragma unroll
            for (int g = 0; g < 4; ++g) {
                const unsigned p0 = cvt_pk_bf16(acc[t][4 * g],     acc[t][4 * g + 1]);
                const unsigned p1 = cvt_pk_bf16(acc[t][4 * g + 2], acc[t][4 * g + 3]);
                *(uint2*)(kr + 8 * g) = make_uint2(p0, p1);
            }
        }
        // V writeback (bf16, transposed): lane = channel c; 4x b64 of 4 consecutive j
#pragma unroll
        for (int t = 2; t < 4; ++t) {
            const int col = (2 * wave + (t & 1)) * 32 + Lm;
            unsigned short* vr = bp + VTOFFB + col * VSTB + 4 * Lh;
#pragma unroll
            for (int g = 0; g < 4; ++g) {
                const unsigned p0 = cvt_pk_bf16(acc[t][4 * g],     acc[t][4 * g + 1]);
                const unsigned p1 = cvt_pk_bf16(acc[t][4 * g + 2], acc[t][4 * g + 3]);
                *(uint2*)(vr + 8 * g) = make_uint2(p0, p1);
            }
        }
    };

    // ---- pipeline prologue: project point 0 into buf0; q(0) into registers ----
    {
        bf16x8 Af[4];
#pragma unroll
        for (int s = 0; s < 4; ++s) Af[s] = pack8(pf[2 * s], pf[2 * s + 1]);

        const int p1 = bid + grid;
        if (p1 < nPoints) {      // issue A-row prefetch for point 1 (flies below)
            const float* arow = inp + (size_t)p1 * (KN * FF) + Lm * FF + Lh * 8;
#pragma unroll
            for (int s = 0; s < 4; ++s) {
                pf[2 * s]     = *(const float4*)(arow + s * 16);
                pf[2 * s + 1] = *(const float4*)(arow + s * 16 + 4);
            }
        }
        project(kvS, Af);
    }
    // q-row for it=0 (2x ds_read_b128, broadcast across head lanes)
    uint4 qA = *(const uint4*)(qAllS + h * 16);
    uint4 qB = *(const uint4*)(qAllS + h * 16 + 8);

    lds_barrier();   // buf0 ready; global prefetch still in flight

    // per-thread constant indices for the attention phase
    const int sR = d & 7;                  // K segment this lane consumes
    const int j0 = 2 * h + (d >> 3);       // K row for k = 2d, 2d+1

    // ============ main loop: attention(i) then projection(i+1), 1 barrier ============
    int cur = 0;
    for (int it = 0, p = bid; p < nPoints; ++it, p += grid) {
        const unsigned short* bc = kvS + cur * HALFB;          // attention buffer
        unsigned short* bn       = kvS + (cur ^ 1) * HALFB;    // projection target
        const int  pn   = p + grid;
        const bool have = (pn < nPoints);                      // block-uniform

        // ---- attention(i): logits. lane (h,d) owns k = 2d, 2d+1 (row j0) ----
        // 4x ds_read_b128 (bf16) covering c = sR*32 .. +31 of K row j0.
        const unsigned short* kb = bc + j0 * KSTRB + sR * 32;
        union { uint4 v; unsigned u[4]; } ckb[4];
#pragma unroll
        for (int w = 0; w < 4; ++w)
            ckb[w].v = *(const uint4*)(kb + 8 * w);

        // unpack Q row (bf16 -> f32), statically indexed
        union { uint4 v; unsigned u[4]; } ua, ub;
        ua.v = qA;  ub.v = qB;
        float qv[16];
#pragma unroll
        for (int j = 0; j < 4; ++j) {
            qv[2 * j]         = bflo(ua.u[j]);
            qv[2 * j + 1]     = bfhi(ua.u[j]);
            qv[8 + 2 * j]     = bflo(ub.u[j]);
            qv[8 + 2 * j + 1] = bfhi(ub.u[j]);
        }

        float l0a = 0.f, l0b = 0.f, l1a = 0.f, l1b = 0.f;
#pragma unroll
        for (int dd = 0; dd < 8; ++dd) {        // dword dd = values i=2dd, 2dd+1
            const unsigned u0 = ckb[dd >> 2].u[dd & 3];        // l0: c = sR*32 + i
            const unsigned u1 = ckb[2 + (dd >> 2)].u[dd & 3];  // l1: c = sR*32+16+i
            l0a = fmaf(qv[2 * dd],     bflo(u0), l0a);
            l0b = fmaf(qv[2 * dd + 1], bfhi(u0), l0b);
            l1a = fmaf(qv[2 * dd],     bflo(u1), l1a);
            l1b = fmaf(qv[2 * dd + 1], bfhi(u1), l1b);
        }
        const float l0 = l0a + l0b;
        const float l1 = l1a + l1b;

        // ---- softmax across the head's 16 lanes ----
        float m = fmaxf(l0, l1);
        m = fmaxf(m, __shfl_xor(m, 1));
        m = fmaxf(m, __shfl_xor(m, 2));
        m = fmaxf(m, __shfl_xor(m, 4));
        m = fmaxf(m, __shfl_xor(m, 8));
        float e0 = __expf(l0 - m), e1 = __expf(l1 - m);
        float s2 = e0 + e1;
        s2 += __shfl_xor(s2, 1);
        s2 += __shfl_xor(s2, 2);
        s2 += __shfl_xor(s2, 4);
        s2 += __shfl_xor(s2, 8);
        const float inv = 1.0f / s2;
        *(float2*)(wS + h * WSTRIDE + 2 * d) = make_float2(e0 * inv, e1 * inv);
        __builtin_amdgcn_wave_barrier();       // intra-wave producer/consumer

        // ---- output: out[h*16+d] = sum_k w[k] * V[j(k), (k&15)*16+d] ----
        float4 wv[8];
#pragma unroll
        for (int g = 0; g < 8; ++g)
            wv[g] = *(const float4*)(wS + h * WSTRIDE + 4 * g);   // broadcast b128

        // Vt[c][j] bf16: pair (k=m, k=m+16) = one dword (j=2h lo, 2h+1 hi)
        const unsigned short* vb = bc + VTOFFB + VSTB * d + 2 * h;
        float o0 = 0.f, o1 = 0.f, o2 = 0.f, o3 = 0.f;
#pragma unroll
        for (int mI = 0; mI < 16; mI += 2) {
            const unsigned va = *(const unsigned*)(vb + 16 * VSTB * mI);
            const unsigned vx = *(const unsigned*)(vb + 16 * VSTB * (mI + 1));
            o0 = fmaf(wv[mI >> 2][mI & 3],                   bflo(va), o0);
            o1 = fmaf(wv[4 + (mI >> 2)][mI & 3],             bfhi(va), o1);
            o2 = fmaf(wv[(mI + 1) >> 2][(mI + 1) & 3],       bflo(vx), o2);
            o3 = fmaf(wv[4 + ((mI + 1) >> 2)][(mI + 1) & 3], bfhi(vx), o3);
        }
        out[(size_t)p * CC + tid] = (o0 + o1) + (o2 + o3);

        // ---- projection(i+1) into bn (no barrier in between: other buffer) ----
        if (have) {
            bf16x8 Af[4];
#pragma unroll
            for (int s = 0; s < 4; ++s) Af[s] = pack8(pf[2 * s], pf[2 * s + 1]);

            const int pn2 = pn + grid;
            if (pn2 < nPoints) {             // prefetch A-row of point i+2
                const float* arow = inp + (size_t)pn2 * (KN * FF) + Lm * FF + Lh * 8;
#pragma unroll
                for (int s = 0; s < 4; ++s) {
                    pf[2 * s]     = *(const float4*)(arow + s * 16);
                    pf[2 * s + 1] = *(const float4*)(arow + s * 16 + 4);
                }
            }
            project(bn, Af);

            // prefetch q-row for it+1 (latency covered by the barrier drain)
            qA = *(const uint4*)(qAllS + (it + 1) * QSTRIDE + h * 16);
            qB = *(const uint4*)(qAllS + (it + 1) * QSTRIDE + h * 16 + 8);
        }

        lds_barrier();   // bn complete everywhere; bc fully consumed
        cur ^= 1;
    }
}

extern "C" void kernel_launch(void* const* d_in, const int* in_sizes, int n_in,
                              void* d_out, int out_size, void* d_ws, size_t ws_size,
                              hipStream_t stream) {
    const float* inp   = (const float*)d_in[0];
    const float* query = (const float*)d_in[1];
    const float* Wq    = (const float*)d_in[2];
    const float* bq    = (const float*)d_in[3];
    const float* Wk    = (const float*)d_in[4];
    const float* bk    = (const float*)d_in[5];
    const float* Wv    = (const float*)d_in[6];
    const float* bv    = (const float*)d_in[7];
    float* out = (float*)d_out;

    const int nPoints = in_sizes[0] / (KN * FF);          // B*N = 16384
    const int grid    = (nPoints + NITER - 1) / NITER;    // 1024

    attn_one<<<grid, 256, 0, stream>>>(inp, query, Wq, bq, Wk, bk, Wv, bv,
                                       out, nPoints);
}

// Round 9
// 248.751 us; speedup vs baseline: 1.1293x; 1.1293x over previous
//
#include <hip/hip_runtime.h>

// Problem constants: B=4, N=4096 -> nPoints=16384
#define KN 32                 // neighbors per point
#define FF 64                 // input feature dim
#define CC 256                // H*D channels (H=16 heads, D=16)
#define KSTRB 264             // K row stride (bf16): K[j][c], 256+8 pad, 528B (16B-aligned)
#define VSTB 36               // Vt row stride (bf16): 32+4 pad, 72B -> 2-way free (R8-validated)
#define VTOFFB (KN * KSTRB)   // Vt base inside kvS (ushorts) = 8448
#define NITER 16              // points per block
#define QSTRIDE 264           // ushorts per qAll row; 528B/row -> b128-aligned per (it,h)
#define WSTRIDE 36            // wS stride in floats: 16B-aligned rows for b128 reads

// Faithful-reshape semantics (validated R1/R2):
//   K[b,n,h,k,d] = K_proj[b,n, j=2h+(k>>4), ch=(k&15)*16+d];  V likewise.
//   Q[b,n,h,0,d] = Q_proj[b,n, h*16+d].
// R9: back to the R7 two-barrier schedule (R8 single-barrier dbuf regressed
// 110->135: no real phase overlap, live-range pressure). Softmax cross-lane
// reduce now uses DPP row_ror (VALU, ~4cyc/step) instead of __shfl_xor
// (ds_bpermute, ~100cyc latency each, 8 serial) — each head is exactly one
// 16-lane DPP row. VSTB=36 keeps the Vt writes/reads at the 2-way bank floor.

typedef __attribute__((ext_vector_type(8)))  short bf16x8;   // 8 bf16 = 4 VGPRs
typedef __attribute__((ext_vector_type(16))) float f32x16;   // 32x32 MFMA acc
typedef __attribute__((ext_vector_type(4)))  float f32x4;    // 16x16 MFMA acc

__device__ inline unsigned short f2bf(float f) {             // fp32->bf16 RNE (prologue only)
    union { float f; unsigned u; } v; v.f = f;
    unsigned u = v.u + 0x7fffu + ((v.u >> 16) & 1u);
    return (unsigned short)(u >> 16);
}
// HW packed fp32->bf16 RNE: 1 instr per pair.
__device__ inline unsigned cvt_pk_bf16(float a, float b) {
    unsigned r;
    asm("v_cvt_pk_bf16_f32 %0, %1, %2" : "=v"(r) : "v"(a), "v"(b));
    return r;
}
__device__ inline bf16x8 pack8(float4 a, float4 b) {
    union { bf16x8 v; unsigned u[4]; } r;
    r.u[0] = cvt_pk_bf16(a.x, a.y);  r.u[1] = cvt_pk_bf16(a.z, a.w);
    r.u[2] = cvt_pk_bf16(b.x, b.y);  r.u[3] = cvt_pk_bf16(b.z, b.w);
    return r.v;
}
__device__ inline float bflo(unsigned u) { return __uint_as_float(u << 16); }
__device__ inline float bfhi(unsigned u) { return __uint_as_float(u & 0xffff0000u); }

// DPP row rotation (within each 16-lane row == one attention head).
// row_ror:N ctrl = 0x120|N; full masks, no bound_ctrl (all lanes active).
#define DPP_ROR(x, N) __int_as_float(__builtin_amdgcn_update_dpp( \
        0, __float_as_int(x), 0x120 | (N), 0xF, 0xF, false))

// LDS producer/consumer barrier WITHOUT the __syncthreads vmcnt(0) drain:
// global prefetches (A-row, out-stores) stay in flight across the barrier.
__device__ inline void lds_barrier() {
    asm volatile("s_waitcnt lgkmcnt(0)" ::: "memory");
    __builtin_amdgcn_s_barrier();
}

// Block = 256 threads (4 waves), NITER points per block.
// Sequential per-point schedule (R1/R7-validated): MFMA -> writeback -> barrier
// -> attention -> barrier. No MFMA acc lives across attention (R2 spill lesson).
__global__ __launch_bounds__(256, 2)
void attn_one(const float* __restrict__ inp,
              const float* __restrict__ query,
              const float* __restrict__ Wq,
              const float* __restrict__ bq,
              const float* __restrict__ Wk,
              const float* __restrict__ bk,
              const float* __restrict__ Wv,
              const float* __restrict__ bv,
              float* __restrict__ out, int nPoints)
{
    __shared__ __align__(16) unsigned short kvS[KN * KSTRB + CC * VSTB]; // 34.5 KB
    __shared__ unsigned short qAllS[NITER * QSTRIDE];                    // 8.25 KB
    __shared__ float wS[16 * WSTRIDE];                                   // 2.25 KB

    const int tid  = threadIdx.x;
    const int wave = tid >> 6;
    const int L    = tid & 63;
    const int Lm   = L & 31;       // M/N index inside the 32x32 tile
    const int Lh   = L >> 5;       // k-half selector (32x32x16)
    const int h    = tid >> 4;     // attention head 0..15
    const int d    = tid & 15;     // dim within head
    const int bid  = blockIdx.x;
    const int grid = gridDim.x;

    // ---- stage this block's 16 query rows into kvS scratch (freed later) ----
    float* qIn = (float*)kvS;      // 16 rows x 68 floats (pad 64->68) = 4.3 KB
    {
        const int i  = tid >> 4;           // point slot 0..15
        const int f4 = (tid & 15) * 4;
        const int p  = bid + i * grid;
        if (p < nPoints)
            *(float4*)(qIn + i * 68 + f4) =
                *(const float4*)(query + (size_t)p * FF + f4);
    }

    // ---- prefetch first point's A-row into registers ----
    float4 pf[8];
    {
        const float* arow = inp + (size_t)bid * (KN * FF) + Lm * FF + Lh * 8;
#pragma unroll
        for (int s = 0; s < 4; ++s) {
            pf[2 * s]     = *(const float4*)(arow + s * 16);
            pf[2 * s + 1] = *(const float4*)(arow + s * 16 + 4);
        }
    }

    // ---- Wk/Wv B fragments (validated R2 layout) ----
    // B[k][n]: lane holds k = s*16 + Lh*8 + j, n = chunk*32 + Lm
    bf16x8 Bf[4][4];   // [tile: K0,K1,V0,V1][kstep]
#pragma unroll
    for (int t = 0; t < 4; ++t) {
        const float* W  = (t < 2) ? Wk : Wv;
        const int ch    = (2 * wave + (t & 1)) * 32 + Lm;
#pragma unroll
        for (int s = 0; s < 4; ++s) {
            union { bf16x8 v; unsigned u[4]; } r;
#pragma unroll
            for (int jj = 0; jj < 4; ++jj) {
                const int f = s * 16 + Lh * 8 + 2 * jj;
                r.u[jj] = cvt_pk_bf16(W[(size_t)f * CC + ch], W[(size_t)(f + 1) * CC + ch]);
            }
            Bf[t][s] = r.v;
        }
    }
    // V-tile bias: acc columns share one channel -> scalar per tile
    float biasV[2];
    biasV[0] = bv[(2 * wave + 0) * 32 + Lm];
    biasV[1] = bv[(2 * wave + 1) * 32 + Lm];
    // K-tile bias: swapped-MFMA rows span channels c = chunk*32 + 8g + 4Lh + e
    float4 bkK[2][4];
#pragma unroll
    for (int t = 0; t < 2; ++t)
#pragma unroll
        for (int g = 0; g < 4; ++g)
            bkK[t][g] = *(const float4*)(bk + (2 * wave + t) * 32 + 8 * g + 4 * Lh);

    // ---- Wq B fragments: 4 N-tiles of 16 per wave, K=64 in 2 steps ----
    const int nq = L & 15;
    const int kq = (L >> 4) * 8;
    bf16x8 Bq[4][2];
    float  bqv[4];
#pragma unroll
    for (int tt = 0; tt < 4; ++tt) {
        const int ch = wave * 64 + tt * 16 + nq;
        bqv[tt] = bq[ch];
#pragma unroll
        for (int s = 0; s < 2; ++s) {
            union { bf16x8 v; unsigned u[4]; } r;
#pragma unroll
            for (int jj = 0; jj < 4; ++jj) {
                const int f = s * 32 + kq + 2 * jj;
                r.u[jj] = cvt_pk_bf16(Wq[(size_t)f * CC + ch], Wq[(size_t)(f + 1) * CC + ch]);
            }
            Bq[tt][s] = r.v;
        }
    }

    __syncthreads();   // qIn staged

    // ---- Q-projection MFMA: M=16 points, N=256 channels, K=64 ----
    {
        bf16x8 Aq[2];
        const int im = L & 15;
#pragma unroll
        for (int s = 0; s < 2; ++s) {
            const float* qr = qIn + im * 68 + s * 32 + kq;
            Aq[s] = pack8(*(const float4*)qr, *(const float4*)(qr + 4));
        }
#pragma unroll
        for (int tt = 0; tt < 4; ++tt) {
            f32x4 qa = {bqv[tt], bqv[tt], bqv[tt], bqv[tt]};  // bias via C
#pragma unroll
            for (int s = 0; s < 2; ++s)
                qa = __builtin_amdgcn_mfma_f32_16x16x32_bf16(Aq[s], Bq[tt][s], qa, 0, 0, 0);
            const int ch = wave * 64 + tt * 16 + nq;
#pragma unroll
            for (int r = 0; r < 4; ++r) {
                const int ip = (L >> 4) * 4 + r;    // point slot 0..15
                qAllS[ip * QSTRIDE + ch] = f2bf(qa[r] * 0.25f);
            }
        }
    }
    __syncthreads();   // qAll ready; kvS scratch free

    // per-thread constant indices for the attention phase
    const int sR  = d & 7;                 // K segment this lane consumes
    const int j0  = 2 * h + (d >> 3);      // K row for k = 2d, 2d+1
    const int vb0 = VTOFFB + VSTB * d + 2 * h;  // Vt read base (ushorts)

    // ================= main loop over this block's points =================
    for (int it = 0, p = bid; p < nPoints; ++it, p += grid) {
        // pack A fragments from prefetched registers
        bf16x8 Af[4];
#pragma unroll
        for (int s = 0; s < 4; ++s) Af[s] = pack8(pf[2 * s], pf[2 * s + 1]);

        // prefetch next point's A-row (stays in flight across lds_barrier)
        const int pn = p + grid;
        if (pn < nPoints) {
            const float* arow = inp + (size_t)pn * (KN * FF) + Lm * FF + Lh * 8;
#pragma unroll
            for (int s = 0; s < 4; ++s) {
                pf[2 * s]     = *(const float4*)(arow + s * 16);
                pf[2 * s + 1] = *(const float4*)(arow + s * 16 + 4);
            }
        }

        // K tiles (0,1): operand-SWAPPED mfma -> D = (X*Wk)^T, col=j, rows=c.
        // V tiles (2,3): normal orientation  -> D = X*Wv,     col=c, rows=j.
        f32x16 acc[4];
#pragma unroll
        for (int t = 0; t < 2; ++t)
#pragma unroll
            for (int g = 0; g < 4; ++g)
#pragma unroll
                for (int e = 0; e < 4; ++e) acc[t][4 * g + e] = bkK[t][g][e];
#pragma unroll
        for (int t = 2; t < 4; ++t)
#pragma unroll
            for (int r = 0; r < 16; ++r) acc[t][r] = biasV[t - 2];

        __builtin_amdgcn_s_setprio(1);
#pragma unroll
        for (int s = 0; s < 4; ++s) {
#pragma unroll
            for (int t = 0; t < 2; ++t)
                acc[t] = __builtin_amdgcn_mfma_f32_32x32x16_bf16(Bf[t][s], Af[s], acc[t], 0, 0, 0);
#pragma unroll
            for (int t = 2; t < 4; ++t)
                acc[t] = __builtin_amdgcn_mfma_f32_32x32x16_bf16(Af[s], Bf[t][s], acc[t], 0, 0, 0);
        }
        __builtin_amdgcn_s_setprio(0);

        // K writeback (bf16): lane = j=Lm; 4x b64 of 4 consecutive channels each
#pragma unroll
        for (int t = 0; t < 2; ++t) {
            unsigned short* kr = kvS + Lm * KSTRB + (2 * wave + t) * 32 + 4 * Lh;
#pragma unroll
            for (int g = 0; g < 4; ++g) {
                const unsigned p0 = cvt_pk_bf16(acc[t][4 * g],     acc[t][4 * g + 1]);
                const unsigned p1 = cvt_pk_bf16(acc[t][4 * g + 2], acc[t][4 * g + 3]);
                *(uint2*)(kr + 8 * g) = make_uint2(p0, p1);
            }
        }
        // V writeback (bf16, transposed): lane = channel c; 4x b64 of 4 consecutive j
#pragma unroll
        for (int t = 2; t < 4; ++t) {
            const int col = (2 * wave + (t & 1)) * 32 + Lm;
            unsigned short* vr = kvS + VTOFFB + col * VSTB + 4 * Lh;
#pragma unroll
            for (int g = 0; g < 4; ++g) {
                const unsigned p0 = cvt_pk_bf16(acc[t][4 * g],     acc[t][4 * g + 1]);
                const unsigned p1 = cvt_pk_bf16(acc[t][4 * g + 2], acc[t][4 * g + 3]);
                *(uint2*)(vr + 8 * g) = make_uint2(p0, p1);
            }
        }

        // early q-row load: 2x ds_read_b128 (broadcast across head lanes)
        const unsigned short* qp = qAllS + it * QSTRIDE + h * 16;
        uint4 qA = *(const uint4*)qp;          // Q[h,0..7]  (bf16 pairs)
        uint4 qB = *(const uint4*)(qp + 8);    // Q[h,8..15]

        lds_barrier();   // kvS(point p) visible; global prefetch still in flight

        // ---- logits: lane (h,d) owns k = 2d, 2d+1 (same neighbor row j0) ----
        // 4x ds_read_b128 (bf16) covering c = sR*32 .. +31 of K row j0.
        const unsigned short* kb = kvS + j0 * KSTRB + sR * 32;
        union { uint4 v; unsigned u[4]; } ckb[4];
#pragma unroll
        for (int w = 0; w < 4; ++w)
            ckb[w].v = *(const uint4*)(kb + 8 * w);

        // unpack Q row (bf16 -> f32), statically indexed
        union { uint4 v; unsigned u[4]; } ua, ub;
        ua.v = qA;  ub.v = qB;
        float qv[16];
#pragma unroll
        for (int j = 0; j < 4; ++j) {
            qv[2 * j]         = bflo(ua.u[j]);
            qv[2 * j + 1]     = bfhi(ua.u[j]);
            qv[8 + 2 * j]     = bflo(ub.u[j]);
            qv[8 + 2 * j + 1] = bfhi(ub.u[j]);
        }

        float l0a = 0.f, l0b = 0.f, l1a = 0.f, l1b = 0.f;
#pragma unroll
        for (int dd = 0; dd < 8; ++dd) {        // dword dd = values i=2dd, 2dd+1
            const unsigned u0 = ckb[dd >> 2].u[dd & 3];        // l0: c = sR*32 + i
            const unsigned u1 = ckb[2 + (dd >> 2)].u[dd & 3];  // l1: c = sR*32+16+i
            l0a = fmaf(qv[2 * dd],     bflo(u0), l0a);
            l0b = fmaf(qv[2 * dd + 1], bfhi(u0), l0b);
            l1a = fmaf(qv[2 * dd],     bflo(u1), l1a);
            l1b = fmaf(qv[2 * dd + 1], bfhi(u1), l1b);
        }
        const float l0 = l0a + l0b;
        const float l1 = l1a + l1b;

        // ---- softmax across the head's 16 lanes: DPP row_ror reduce (VALU) ----
        float m = fmaxf(l0, l1);
        m = fmaxf(m, DPP_ROR(m, 8));
        m = fmaxf(m, DPP_ROR(m, 4));
        m = fmaxf(m, DPP_ROR(m, 2));
        m = fmaxf(m, DPP_ROR(m, 1));
        float e0 = __expf(l0 - m), e1 = __expf(l1 - m);
        float s2 = e0 + e1;
        s2 += DPP_ROR(s2, 8);
        s2 += DPP_ROR(s2, 4);
        s2 += DPP_ROR(s2, 2);
        s2 += DPP_ROR(s2, 1);
        const float inv = 1.0f / s2;
        *(float2*)(wS + h * WSTRIDE + 2 * d) = make_float2(e0 * inv, e1 * inv);
        __builtin_amdgcn_wave_barrier();       // intra-wave producer/consumer

        // ---- output: out[h*16+d] = sum_k w[k] * V[j(k), (k&15)*16+d] ----
        float4 wv[8];
#pragma unroll
        for (int g = 0; g < 8; ++g)
            wv[g] = *(const float4*)(wS + h * WSTRIDE + 4 * g);   // broadcast b128

        // Vt[c][j] bf16: pair (k=m, k=m+16) = one dword (j=2h lo, 2h+1 hi)
        float o0 = 0.f, o1 = 0.f, o2 = 0.f, o3 = 0.f;
#pragma unroll
        for (int mI = 0; mI < 16; mI += 2) {
            const unsigned va = *(const unsigned*)(kvS + vb0 + 16 * VSTB * mI);
            const unsigned vx = *(const unsigned*)(kvS + vb0 + 16 * VSTB * (mI + 1));
            o0 = fmaf(wv[mI >> 2][mI & 3],                   bflo(va), o0);
            o1 = fmaf(wv[4 + (mI >> 2)][mI & 3],             bfhi(va), o1);
            o2 = fmaf(wv[(mI + 1) >> 2][(mI + 1) & 3],       bflo(vx), o2);
            o3 = fmaf(wv[4 + ((mI + 1) >> 2)][(mI + 1) & 3], bfhi(vx), o3);
        }
        out[(size_t)p * CC + tid] = (o0 + o1) + (o2 + o3);

        lds_barrier();   // kvS fully consumed before next point overwrites
    }
}

extern "C" void kernel_launch(void* const* d_in, const int* in_sizes, int n_in,
                              void* d_out, int out_size, void* d_ws, size_t ws_size,
                              hipStream_t stream) {
    const float* inp   = (const float*)d_in[0];
    const float* query = (const float*)d_in[1];
    const float* Wq    = (const float*)d_in[2];
    const float* bq    = (const float*)d_in[3];
    const float* Wk    = (const float*)d_in[4];
    const float* bk    = (const float*)d_in[5];
    const float* Wv    = (const float*)d_in[6];
    const float* bv    = (const float*)d_in[7];
    float* out = (float*)d_out;

    const int nPoints = in_sizes[0] / (KN * FF);          // B*N = 16384
    const int grid    = (nPoints + NITER - 1) / NITER;    // 1024

    attn_one<<<grid, 256, 0, stream>>>(inp, query, Wq, bq, Wk, bk, Wv, bv,
                                       out, nPoints);
}